// Round 7
// baseline (1074.385 us; speedup 1.0000x reference)
//
#include <hip/hip_runtime.h>
#include <hip/hip_bf16.h>

// AttributeGNN, bf16 MFMA, fp32 accumulate. B=16384, A=16, D=256.
// R7: ABLATION ROUND. Pipeline is bit-identical to R6 (716us baseline).
// Four probe kernels appended (write only dead ws regions, after reduce_indiv):
//   probe_stream: linear f32x4 read of edge           -> HBM best case
//   probe_tile:   k1 staging+bounce+store, no GEMM    -> staging cost
//   probe_gemm:   k1 GEMM+bounce+store, no staging    -> GEMM-path cost
//   probe_gll:    staging via async global_load_lds   -> candidate fix

typedef __bf16 bf16_t;
typedef __bf16 bf16x4 __attribute__((ext_vector_type(4)));
typedef __bf16 bf16x8 __attribute__((ext_vector_type(8)));
typedef float f32x4 __attribute__((ext_vector_type(4)));

#define NB 16384
#define NA 16
#define ND 256

__device__ __forceinline__ int swz(int r, int c) {
    return r * 256 + (c ^ ((r & 7) << 3));
}

// Per-wave 32(M) x 256(K) x 64(N-slice) GEMM. A from swizzled LDS.
// B from global in FRAGMENT layout (1KB coalesced per fragment load).
__device__ __forceinline__ void gemm64(const bf16_t* a_lds, const bf16_t* __restrict__ Bf,
                                       f32x4 acc[2][4], int lane, int wc)
{
    const int lr = lane & 15, lhi = lane >> 4;
    const bf16_t* bp = Bf + wc * 16384 + lane * 8;
    bf16x8 bq[2][4];
#pragma unroll
    for (int p = 0; p < 2; ++p)
#pragma unroll
        for (int ni = 0; ni < 4; ++ni)
            bq[p][ni] = *(const bf16x8*)&bp[(ni * 8 + p) * 512];
#pragma unroll
    for (int ks = 0; ks < 8; ++ks) {
        const int kc = ks * 32 + lhi * 8;
        bf16x8 af0 = *(const bf16x8*)&a_lds[swz(lr, kc)];
        bf16x8 af1 = *(const bf16x8*)&a_lds[swz(16 + lr, kc)];
#pragma unroll
        for (int ni = 0; ni < 4; ++ni) {
            acc[0][ni] = __builtin_amdgcn_mfma_f32_16x16x32_bf16(af0, bq[ks & 1][ni], acc[0][ni], 0, 0, 0);
            acc[1][ni] = __builtin_amdgcn_mfma_f32_16x16x32_bf16(af1, bq[ks & 1][ni], acc[1][ni], 0, 0, 0);
        }
        if (ks + 2 < 8) {
#pragma unroll
            for (int ni = 0; ni < 4; ++ni)
                bq[ks & 1][ni] = *(const bf16x8*)&bp[(ni * 8 + ks + 2) * 512];
        }
    }
}

__device__ __forceinline__ void stage32(const float* __restrict__ base, size_t rstride,
                                        bf16_t* dst, int tid)
{
    const int srr = tid >> 6;
    const int sc4 = (tid & 63) * 4;
#pragma unroll
    for (int h = 0; h < 2; ++h) {
        f32x4 sv[4];
#pragma unroll
        for (int it = 0; it < 4; ++it)
            sv[it] = *(const f32x4*)(base + (size_t)(srr + (h * 4 + it) * 4) * rstride + sc4);
#pragma unroll
        for (int it = 0; it < 4; ++it) {
            int r = srr + (h * 4 + it) * 4;
            bf16x4 s = {(bf16_t)sv[it].x, (bf16_t)sv[it].y, (bf16_t)sv[it].z, (bf16_t)sv[it].w};
            *(bf16x4*)&dst[swz(r, sc4)] = s;
        }
    }
}

__global__ void prep_wfrag(const float* __restrict__ W,
                           bf16_t* __restrict__ W1f, bf16_t* __restrict__ W2f)
{
    int t = blockIdx.x * 256 + threadIdx.x;
    int lane = t & 63;
    int ks = (t >> 6) & 7;
    int nt = (t >> 9) & 15;
    int half = t >> 13;
    int row = nt * 16 + (lane & 15);
    int col = ks * 32 + (lane >> 4) * 8;
    const float* src = W + (size_t)row * 512 + half * 256 + col;
    bf16_t* dst = (half ? W2f : W1f) + ((nt * 8 + ks) * 64 + lane) * 8;
    bf16x8 v;
#pragma unroll
    for (int m = 0; m < 8; ++m) v[m] = (bf16_t)src[m];
    *(bf16x8*)dst = v;
}

__global__ void transpose_P(const float* __restrict__ Pf, const float* __restrict__ Pb,
                            bf16_t* __restrict__ Pft, bf16_t* __restrict__ Pbt)
{
    __shared__ float t[32][33];
    int blk = blockIdx.x;
    int mat = blk >> 10;
    int rest = blk & 1023;
    int a = rest >> 6;
    int tile = rest & 63;
    int i0 = (tile >> 3) * 32;
    int j0 = (tile & 7) * 32;
    const float* src = (mat ? Pb : Pf) + a * 65536;
    bf16_t* dst = (mat ? Pbt : Pft) + a * 65536;
    int r = threadIdx.x >> 5, c = threadIdx.x & 31;
#pragma unroll
    for (int it = 0; it < 4; ++it)
        t[r + 8 * it][c] = src[(i0 + r + 8 * it) * 256 + j0 + c];
    __syncthreads();
#pragma unroll
    for (int it = 0; it < 4; ++it)
        dst[(j0 + r + 8 * it) * 256 + i0 + c] = (bf16_t)t[c][r + 8 * it];
}

__global__ void prep_pfrag(const bf16_t* __restrict__ Pt, bf16_t* __restrict__ Pfr)
{
    int t = blockIdx.x * 256 + threadIdx.x;
    int lane = t & 63;
    int ks = (t >> 6) & 7;
    int nt = (t >> 9) & 15;
    int a = t >> 13;
    bf16x8 v = *(const bf16x8*)&Pt[(size_t)a * 65536 + (nt * 16 + (lane & 15)) * 256 + ks * 32 + (lane >> 4) * 8];
    *(bf16x8*)&Pfr[(size_t)a * 65536 + ((nt * 8 + ks) * 64 + lane) * 8] = v;
}

__global__ __launch_bounds__(256, 3)
void k1_agg(const float* __restrict__ img, const float* __restrict__ bias,
            const float* __restrict__ edge,
            const bf16_t* __restrict__ W1f, const bf16_t* __restrict__ W2f,
            bf16_t* __restrict__ aggws)
{
    __shared__ bf16_t E[2][32 * 256];
    __shared__ bf16_t O[32 * 256];

    const int tid = threadIdx.x;
    const int lane = tid & 63;
    const int wc = tid >> 6;
    const int lr = lane & 15;
    const int lhi = lane >> 4;
    const int brow0 = blockIdx.x * 32;
    const int a0 = blockIdx.y * 8;

    stage32(img + (size_t)brow0 * ND, ND, &E[0][0], tid);
    __syncthreads();

    f32x4 T[2][4];
#pragma unroll
    for (int ni = 0; ni < 4; ++ni) {
        float bz = bias[wc * 64 + ni * 16 + lr];
        T[0][ni] = (f32x4){bz, bz, bz, bz};
        T[1][ni] = (f32x4){bz, bz, bz, bz};
    }
    gemm64(&E[0][0], W1f, T, lane, wc);
    __syncthreads();

    stage32(edge + (size_t)brow0 * (NA * ND) + (size_t)a0 * ND, NA * ND, &E[0][0], tid);
    __syncthreads();

    for (int ai = 0; ai < 8; ++ai) {
        const int a = a0 + ai;
        const int cur = ai & 1;
        if (ai + 1 < 8)
            stage32(edge + (size_t)brow0 * (NA * ND) + (size_t)(a + 1) * ND, NA * ND,
                    &E[cur ^ 1][0], tid);
        f32x4 acc[2][4];
#pragma unroll
        for (int mi = 0; mi < 2; ++mi)
#pragma unroll
            for (int ni = 0; ni < 4; ++ni)
                acc[mi][ni] = T[mi][ni];
        gemm64(&E[cur][0], W2f, acc, lane, wc);

#pragma unroll
        for (int mi = 0; mi < 2; ++mi)
#pragma unroll
            for (int ni = 0; ni < 4; ++ni)
#pragma unroll
                for (int j = 0; j < 4; ++j)
                    O[swz(mi * 16 + lhi * 4 + j, wc * 64 + ni * 16 + lr)] = (bf16_t)acc[mi][ni][j];
        __syncthreads();

        {
            bf16_t* op = aggws + ((size_t)a * NB + brow0) * ND;
            const int r = tid >> 3;
            const int cb = (tid & 7) * 32;
#pragma unroll
            for (int q = 0; q < 4; ++q) {
                bf16x8 v = *(const bf16x8*)&O[swz(r, cb + q * 8)];
                *(bf16x8*)&op[(size_t)r * ND + cb + q * 8] = v;
            }
        }
        __syncthreads();
    }
}

__global__ __launch_bounds__(256, 4)
void k2_attr(const bf16_t* __restrict__ aggws, const bf16_t* __restrict__ Pff,
             float* __restrict__ out)
{
    __shared__ bf16_t S[32 * 256];

    const int tid = threadIdx.x;
    const int lane = tid & 63;
    const int wc = tid >> 6;
    const int lr = lane & 15;
    const int lhi = lane >> 4;
    const int a = blockIdx.x >> 9;
    const int brow0 = (blockIdx.x & 511) * 32;

    {
        const bf16_t* src = aggws + ((size_t)a * NB + brow0) * ND;
        const int r = tid >> 3;
        const int cb = (tid & 7) * 32;
#pragma unroll
        for (int q = 0; q < 4; ++q) {
            bf16x8 v = *(const bf16x8*)&src[(size_t)r * ND + cb + q * 8];
            *(bf16x8*)&S[swz(r, cb + q * 8)] = v;
        }
    }
    __syncthreads();

    f32x4 acc[2][4];
#pragma unroll
    for (int mi = 0; mi < 2; ++mi)
#pragma unroll
        for (int ni = 0; ni < 4; ++ni)
            acc[mi][ni] = (f32x4){0.f, 0.f, 0.f, 0.f};
    gemm64(&S[0], Pff + (size_t)a * 65536, acc, lane, wc);

    float* op = out + ((size_t)brow0 * NA + a) * ND;
#pragma unroll
    for (int mi = 0; mi < 2; ++mi)
#pragma unroll
        for (int ni = 0; ni < 4; ++ni)
#pragma unroll
            for (int j = 0; j < 4; ++j) {
                int r = mi * 16 + lhi * 4 + j;
                int c = wc * 64 + ni * 16 + lr;
                op[(size_t)r * (NA * ND) + c] = acc[mi][ni][j];
            }
}

__global__ __launch_bounds__(256, 3)
void k3_indiv(const float* attr, const bf16_t* __restrict__ Pbf,
              const float* __restrict__ sw, float* __restrict__ out,
              float* __restrict__ part)
{
    __shared__ bf16_t S[2][32 * 256];

    const int tid = threadIdx.x;
    const int lane = tid & 63;
    const int wc = tid >> 6;
    const int lr = lane & 15;
    const int lhi = lane >> 4;
    const int brow0 = blockIdx.x * 32;
    const int a0 = blockIdx.y * 8;

    stage32(attr + (size_t)brow0 * (NA * ND) + (size_t)a0 * ND, NA * ND, &S[0][0], tid);
    __syncthreads();

    f32x4 indiv[2][4];
#pragma unroll
    for (int mi = 0; mi < 2; ++mi)
#pragma unroll
        for (int ni = 0; ni < 4; ++ni)
            indiv[mi][ni] = (f32x4){0.f, 0.f, 0.f, 0.f};

    for (int ai = 0; ai < 8; ++ai) {
        const int a = a0 + ai;
        const int cur = ai & 1;
        if (ai + 1 < 8)
            stage32(attr + (size_t)brow0 * (NA * ND) + (size_t)(a + 1) * ND, NA * ND,
                    &S[cur ^ 1][0], tid);
        f32x4 acc[2][4];
#pragma unroll
        for (int mi = 0; mi < 2; ++mi)
#pragma unroll
            for (int ni = 0; ni < 4; ++ni)
                acc[mi][ni] = (f32x4){0.f, 0.f, 0.f, 0.f};
        gemm64(&S[cur][0], Pbf + (size_t)a * 65536, acc, lane, wc);
        const float swa = sw[a];
#pragma unroll
        for (int mi = 0; mi < 2; ++mi)
#pragma unroll
            for (int ni = 0; ni < 4; ++ni)
#pragma unroll
                for (int j = 0; j < 4; ++j)
                    indiv[mi][ni][j] += fmaxf(acc[mi][ni][j], 0.f) * swa;
        __syncthreads();
    }

    float* ind = (blockIdx.y == 0) ? out : part;
#pragma unroll
    for (int mi = 0; mi < 2; ++mi)
#pragma unroll
        for (int ni = 0; ni < 4; ++ni)
#pragma unroll
            for (int j = 0; j < 4; ++j) {
                int r = mi * 16 + lhi * 4 + j;
                int c = wc * 64 + ni * 16 + lr;
                ind[(size_t)(brow0 + r) * ND + c] = indiv[mi][ni][j];
            }
}

__global__ void reduce_indiv(float* __restrict__ outI, const float* __restrict__ part)
{
    size_t i = ((size_t)blockIdx.x * 256 + threadIdx.x) * 4;
    f32x4 a = *(const f32x4*)&outI[i];
    f32x4 b = *(const f32x4*)&part[i];
    a.x += b.x; a.y += b.y; a.z += b.z; a.w += b.w;
    *(f32x4*)&outI[i] = a;
}

// ======================= PROBES (write only dead ws) =======================

// P1: best-case linear stream of edge (268 MB).
__global__ __launch_bounds__(256, 8)
void probe_stream(const float* __restrict__ src, float* __restrict__ sink)
{
    size_t base = (size_t)blockIdx.x * 256 + threadIdx.x;
    const f32x4* p = (const f32x4*)src;
    float s = 0.f;
#pragma unroll 8
    for (int it = 0; it < 32; ++it) {
        f32x4 v = p[base + (size_t)it * 524288];
        s += v.x + v.y + v.z + v.w;
    }
    sink[base] = s;
}

// P2: k1's staging+bounce+store loop with the GEMM deleted.
__global__ __launch_bounds__(256, 3)
void probe_tile(const float* __restrict__ edge, bf16_t* __restrict__ scratch)
{
    __shared__ bf16_t E[2][32 * 256];
    __shared__ bf16_t O[32 * 256];
    const int tid = threadIdx.x;
    const int lane = tid & 63;
    const int wc = tid >> 6;
    const int lr = lane & 15;
    const int lhi = lane >> 4;
    const int brow0 = blockIdx.x * 32;
    const int a0 = blockIdx.y * 8;

    stage32(edge + (size_t)brow0 * (NA * ND) + (size_t)a0 * ND, NA * ND, &E[0][0], tid);
    __syncthreads();

    float acc = 0.f;
    for (int ai = 0; ai < 8; ++ai) {
        const int cur = ai & 1;
        if (ai + 1 < 8)
            stage32(edge + (size_t)brow0 * (NA * ND) + (size_t)(a0 + ai + 1) * ND, NA * ND,
                    &E[cur ^ 1][0], tid);
        // consume the staged tile (keeps it live, stands in for GEMM A-reads)
        float local = 0.f;
#pragma unroll
        for (int q = 0; q < 4; ++q) {
            bf16x8 v = *(const bf16x8*)&E[cur][swz(tid >> 3, (tid & 7) * 32 + q * 8)];
            local += (float)v[0] + (float)v[3] + (float)v[7];
        }
        acc += local;
        // bounce pattern identical to k1 (32 scattered bf16 writes/thread)
#pragma unroll
        for (int mi = 0; mi < 2; ++mi)
#pragma unroll
            for (int ni = 0; ni < 4; ++ni)
#pragma unroll
                for (int j = 0; j < 4; ++j)
                    O[swz(mi * 16 + lhi * 4 + j, wc * 64 + ni * 16 + lr)] = (bf16_t)local;
        __syncthreads();
        {
            bf16_t* op = scratch + ((size_t)(a0 + ai) * NB + brow0) * ND;
            const int r = tid >> 3;
            const int cb = (tid & 7) * 32;
#pragma unroll
            for (int q = 0; q < 4; ++q) {
                bf16x8 v = *(const bf16x8*)&O[swz(r, cb + q * 8)];
                *(bf16x8*)&op[(size_t)r * ND + cb + q * 8] = v;
            }
        }
        __syncthreads();
    }
    asm volatile("" :: "v"(acc));
}

// P3: k1's GEMM+bounce+store loop with per-iter staging deleted (one tile reused).
__global__ __launch_bounds__(256, 3)
void probe_gemm(const float* __restrict__ edge, const bf16_t* __restrict__ W2f,
                bf16_t* __restrict__ scratch)
{
    __shared__ bf16_t E[2][32 * 256];
    __shared__ bf16_t O[32 * 256];
    const int tid = threadIdx.x;
    const int lane = tid & 63;
    const int wc = tid >> 6;
    const int lr = lane & 15;
    const int lhi = lane >> 4;
    const int brow0 = blockIdx.x * 32;
    const int a0 = blockIdx.y * 8;

    stage32(edge + (size_t)brow0 * (NA * ND) + (size_t)a0 * ND, NA * ND, &E[0][0], tid);
    __syncthreads();

    for (int ai = 0; ai < 8; ++ai) {
        f32x4 acc[2][4];
#pragma unroll
        for (int mi = 0; mi < 2; ++mi)
#pragma unroll
            for (int ni = 0; ni < 4; ++ni)
                acc[mi][ni] = (f32x4){0.f, 0.f, 0.f, 0.f};
        gemm64(&E[0][0], W2f, acc, lane, wc);
#pragma unroll
        for (int mi = 0; mi < 2; ++mi)
#pragma unroll
            for (int ni = 0; ni < 4; ++ni)
#pragma unroll
                for (int j = 0; j < 4; ++j)
                    O[swz(mi * 16 + lhi * 4 + j, wc * 64 + ni * 16 + lr)] = (bf16_t)acc[mi][ni][j];
        __syncthreads();
        {
            bf16_t* op = scratch + ((size_t)(a0 + ai) * NB + brow0) * ND;
            const int r = tid >> 3;
            const int cb = (tid & 7) * 32;
#pragma unroll
            for (int q = 0; q < 4; ++q) {
                bf16x8 v = *(const bf16x8*)&O[swz(r, cb + q * 8)];
                *(bf16x8*)&op[(size_t)r * ND + cb + q * 8] = v;
            }
        }
        __syncthreads();
    }
}

// P4: staging via async global_load_lds (fp32, width 16, linear LDS dest).
__device__ __forceinline__ void gll16(const void* g, void* l)
{
    __builtin_amdgcn_global_load_lds((const __attribute__((address_space(1))) unsigned int*)g,
                                     (__attribute__((address_space(3))) unsigned int*)l,
                                     16, 0, 0);
}

__global__ __launch_bounds__(256, 3)
void probe_gll(const float* __restrict__ edge, float* __restrict__ sink)
{
    __shared__ float Ef[32 * 256];      // 32 KB, one edge tile fp32, linear
    const int tid = threadIdx.x;
    const int lane = tid & 63;
    const int wave = tid >> 6;
    const int brow0 = blockIdx.x * 32;
    const int a0 = blockIdx.y * 8;

    float acc = 0.f;
    for (int ai = 0; ai < 8; ++ai) {
        // each wave stages 8 rows: LDS chunk c = wave*8+i (1KB) <- edge row brow0+c
#pragma unroll
        for (int i = 0; i < 8; ++i) {
            const int c = wave * 8 + i;
            const float* g = edge + (size_t)(brow0 + c) * (NA * ND) + (size_t)(a0 + ai) * ND + lane * 4;
            gll16(g, &Ef[c * 256]);
        }
        __syncthreads();                // drains vmcnt before barrier (compiler)
        float local = 0.f;
#pragma unroll
        for (int q = 0; q < 4; ++q)
            local += Ef[tid + q * 2048];
        acc += local;
        __syncthreads();
    }
    sink[(size_t)(blockIdx.y * 512 + blockIdx.x) * 256 + tid] = acc;
}

extern "C" void kernel_launch(void* const* d_in, const int* in_sizes, int n_in,
                              void* d_out, int out_size, void* d_ws, size_t ws_size,
                              hipStream_t stream)
{
    const float* img  = (const float*)d_in[0];
    const float* edge = (const float*)d_in[1];
    const float* Wagg = (const float*)d_in[2];
    const float* bagg = (const float*)d_in[3];
    const float* Pf   = (const float*)d_in[4];
    const float* Pb   = (const float*)d_in[5];
    const float* sw   = (const float*)d_in[6];
    float* out = (float*)d_out;

    char* ws = (char*)d_ws;
    bf16_t* W1f = (bf16_t*)(ws);                   // 128 KB
    bf16_t* W2f = (bf16_t*)(ws + 131072);          // 128 KB
    bf16_t* Pff = (bf16_t*)(ws + 262144);          // 2 MB
    bf16_t* Pbf = (bf16_t*)(ws + 2359296);         // 2 MB
    bf16_t* agg = (bf16_t*)(ws + 4456448);         // 134.2 MB
    bf16_t* Ptf  = (bf16_t*)(ws + 4456448);        // temp, dead before k1
    bf16_t* Ptb  = (bf16_t*)(ws + 6553600);        // temp, dead before k1
    float*  part = (float*)(ws + 4456448);         // aliases agg (k2 done first)

    // ---- real pipeline (identical to R6) ----
    prep_wfrag<<<64, 256, 0, stream>>>(Wagg, W1f, W2f);
    transpose_P<<<2048, 256, 0, stream>>>(Pf, Pb, Ptf, Ptb);
    prep_pfrag<<<512, 256, 0, stream>>>(Ptf, Pff);
    prep_pfrag<<<512, 256, 0, stream>>>(Ptb, Pbf);
    k1_agg<<<dim3(NB / 32, 2), 256, 0, stream>>>(img, bagg, edge, W1f, W2f, agg);
    k2_attr<<<NA * (NB / 32), 256, 0, stream>>>(agg, Pff, out);
    k3_indiv<<<dim3(NB / 32, 2), 256, 0, stream>>>(out, Pbf, sw,
                                                   out + (size_t)NB * NA * ND, part);
    reduce_indiv<<<4096, 256, 0, stream>>>(out + (size_t)NB * NA * ND, part);

    // ---- probes: run last; everything in ws is dead now; d_out untouched ----
    float*  ps_sink  = (float*)(ws + 262144);           // over Pff (dead), 2 MB
    float*  gll_sink = (float*)(ws + 2359296);          // over Pbf (dead), 1 MB
    bf16_t* pt_scr   = (bf16_t*)(ws + 4456448);         // over agg (dead), 134 MB

    probe_stream<<<2048, 256, 0, stream>>>(edge, ps_sink);
    probe_tile<<<dim3(512, 2), 256, 0, stream>>>(edge, pt_scr);
    probe_gemm<<<dim3(512, 2), 256, 0, stream>>>(edge, W2f, pt_scr);
    probe_gll<<<dim3(512, 2), 256, 0, stream>>>(edge, gll_sink);
}

// Round 8
// 421.406 us; speedup vs baseline: 2.5495x; 2.5495x over previous
//
#include <hip/hip_runtime.h>
#include <hip/hip_bf16.h>

// AttributeGNN, bf16 MFMA, fp32 accumulate. B=16384, A=16, D=256.
// R8: strided-read elimination. edge pre-transposed to [a][b][d] bf16 (linear
// 16KB/tile reads); ONE fused kernel (no agg/attr ws round-trips); W1/W2 held
// in registers per wave (GEMM1 has zero vmem -> no vmcnt coupling with edge
// prefetch); Pf/Pb read as 1KB-coalesced L2-resident fragments.

typedef __bf16 bf16_t;
typedef __bf16 bf16x4 __attribute__((ext_vector_type(4)));
typedef __bf16 bf16x8 __attribute__((ext_vector_type(8)));
typedef float f32x4 __attribute__((ext_vector_type(4)));

#define NB 16384
#define NA 16
#define ND 256

// XOR swizzle for bf16 LDS tiles [32][256]: 8-row stripes spread across 8
// distinct 16B slots; 16-lane column reads -> 2-way (free per m136).
__device__ __forceinline__ int swz(int r, int c) {
    return r * 256 + (c ^ ((r & 7) << 3));
}

__device__ __forceinline__ bf16x8 cvt8(f32x4 a, f32x4 b) {
    bf16x8 r;
    r[0] = (bf16_t)a.x; r[1] = (bf16_t)a.y; r[2] = (bf16_t)a.z; r[3] = (bf16_t)a.w;
    r[4] = (bf16_t)b.x; r[5] = (bf16_t)b.y; r[6] = (bf16_t)b.z; r[7] = (bf16_t)b.w;
    return r;
}

// 32(M) x 256(K) x 32(N-slice) GEMM, B held in registers (W[ni][ks]).
// C/D layout per m89: col = lane&15, row = (lane>>4)*4 + j.
__device__ __forceinline__ void gemm32r(const bf16_t* a_lds, const bf16x8 (&W)[2][8],
                                        f32x4 acc[2][2], int lane)
{
    const int lr = lane & 15, lhi = lane >> 4;
#pragma unroll
    for (int ks = 0; ks < 8; ++ks) {
        const int kc = ks * 32 + lhi * 8;
        bf16x8 af0 = *(const bf16x8*)&a_lds[swz(lr, kc)];
        bf16x8 af1 = *(const bf16x8*)&a_lds[swz(16 + lr, kc)];
        acc[0][0] = __builtin_amdgcn_mfma_f32_16x16x32_bf16(af0, W[0][ks], acc[0][0], 0, 0, 0);
        acc[1][0] = __builtin_amdgcn_mfma_f32_16x16x32_bf16(af1, W[0][ks], acc[1][0], 0, 0, 0);
        acc[0][1] = __builtin_amdgcn_mfma_f32_16x16x32_bf16(af0, W[1][ks], acc[0][1], 0, 0, 0);
        acc[1][1] = __builtin_amdgcn_mfma_f32_16x16x32_bf16(af1, W[1][ks], acc[1][1], 0, 0, 0);
    }
}

// Same, B from global fragment layout (L2-resident), depth-2 register pipeline.
// frag(nt, ks) occupies 512 consecutive bf16; nt = wc*2 + ni.
__device__ __forceinline__ void gemm32g(const bf16_t* a_lds, const bf16_t* __restrict__ Bf,
                                        f32x4 acc[2][2], int lane, int wc)
{
    const int lr = lane & 15, lhi = lane >> 4;
    const bf16_t* bp = Bf + (size_t)wc * 16 * 512 + lane * 8;
    bf16x8 b0a = *(const bf16x8*)&bp[0 * 512];
    bf16x8 b1a = *(const bf16x8*)&bp[8 * 512];
    bf16x8 b0b = *(const bf16x8*)&bp[1 * 512];
    bf16x8 b1b = *(const bf16x8*)&bp[9 * 512];
#pragma unroll
    for (int ks = 0; ks < 8; ++ks) {
        const int kc = ks * 32 + lhi * 8;
        bf16x8 af0 = *(const bf16x8*)&a_lds[swz(lr, kc)];
        bf16x8 af1 = *(const bf16x8*)&a_lds[swz(16 + lr, kc)];
        bf16x8 c0 = (ks & 1) ? b0b : b0a;
        bf16x8 c1 = (ks & 1) ? b1b : b1a;
        acc[0][0] = __builtin_amdgcn_mfma_f32_16x16x32_bf16(af0, c0, acc[0][0], 0, 0, 0);
        acc[1][0] = __builtin_amdgcn_mfma_f32_16x16x32_bf16(af1, c0, acc[1][0], 0, 0, 0);
        acc[0][1] = __builtin_amdgcn_mfma_f32_16x16x32_bf16(af0, c1, acc[0][1], 0, 0, 0);
        acc[1][1] = __builtin_amdgcn_mfma_f32_16x16x32_bf16(af1, c1, acc[1][1], 0, 0, 0);
        if (ks + 2 < 8) {
            if (ks & 1) {
                b0b = *(const bf16x8*)&bp[(ks + 2) * 512];
                b1b = *(const bf16x8*)&bp[(8 + ks + 2) * 512];
            } else {
                b0a = *(const bf16x8*)&bp[(ks + 2) * 512];
                b1a = *(const bf16x8*)&bp[(8 + ks + 2) * 512];
            }
        }
    }
}

// ---- W_agg [256][512] fp32 -> W1f / W2f fragment layout (bf16).
__global__ void prep_wfrag(const float* __restrict__ W,
                           bf16_t* __restrict__ W1f, bf16_t* __restrict__ W2f)
{
    int t = blockIdx.x * 256 + threadIdx.x;
    int lane = t & 63;
    int ks = (t >> 6) & 7;
    int nt = (t >> 9) & 15;
    int half = t >> 13;
    int row = nt * 16 + (lane & 15);
    int col = ks * 32 + (lane >> 4) * 8;
    const float* src = W + (size_t)row * 512 + half * 256 + col;
    bf16_t* dst = (half ? W2f : W1f) + ((nt * 8 + ks) * 64 + lane) * 8;
    bf16x8 v;
#pragma unroll
    for (int m = 0; m < 8; ++m) v[m] = (bf16_t)src[m];
    *(bf16x8*)dst = v;
}

// ---- P[a][i][j] fp32 -> Pt[a][j][i] bf16 via LDS transpose.
__global__ void transpose_P(const float* __restrict__ Pf, const float* __restrict__ Pb,
                            bf16_t* __restrict__ Pft, bf16_t* __restrict__ Pbt)
{
    __shared__ float t[32][33];
    int blk = blockIdx.x;
    int mat = blk >> 10;
    int rest = blk & 1023;
    int a = rest >> 6;
    int tile = rest & 63;
    int i0 = (tile >> 3) * 32;
    int j0 = (tile & 7) * 32;
    const float* src = (mat ? Pb : Pf) + a * 65536;
    bf16_t* dst = (mat ? Pbt : Pft) + a * 65536;
    int r = threadIdx.x >> 5, c = threadIdx.x & 31;
#pragma unroll
    for (int it = 0; it < 4; ++it)
        t[r + 8 * it][c] = src[(i0 + r + 8 * it) * 256 + j0 + c];
    __syncthreads();
#pragma unroll
    for (int it = 0; it < 4; ++it)
        dst[(j0 + r + 8 * it) * 256 + i0 + c] = (bf16_t)t[c][r + 8 * it];
}

// ---- row-major bf16 [16][256][256] -> fragment layout.
__global__ void prep_pfrag(const bf16_t* __restrict__ Pt, bf16_t* __restrict__ Pfr)
{
    int t = blockIdx.x * 256 + threadIdx.x;
    int lane = t & 63;
    int ks = (t >> 6) & 7;
    int nt = (t >> 9) & 15;
    int a = t >> 13;
    bf16x8 v = *(const bf16x8*)&Pt[(size_t)a * 65536 + (nt * 16 + (lane & 15)) * 256 + ks * 32 + (lane >> 4) * 8];
    *(bf16x8*)&Pfr[(size_t)a * 65536 + ((nt * 8 + ks) * 64 + lane) * 8] = v;
}

// ---- edge [b][a][d] fp32 -> edgeT [a][b][d] bf16. Linear reads; writes in
// 512B wave-chunks, plane-consecutive (L2 write-back aggregates).
__global__ void edge_tr(const float* __restrict__ edge, bf16_t* __restrict__ edgeT)
{
    size_t t = (size_t)blockIdx.x * 256 + threadIdx.x;  // 8.4M threads, 8 elems each
    size_t b = t >> 9;
    int a = (int)((t >> 5) & 15);
    int d8 = (int)(t & 31);
    const float* src = edge + (b << 12) + (a << 8) + (d8 << 3);
    f32x4 v0 = *(const f32x4*)src;
    f32x4 v1 = *(const f32x4*)(src + 4);
    *(bf16x8*)&edgeT[(((size_t)a << 14) + b) * 256 + (d8 << 3)] = cvt8(v0, v1);
}

// ---- fused main: per 32-row block, loop a=0..15:
//   phase1 GEMM1 (W2 in regs, edge from LDS) -> G;  prefetch edge(a+1)
//   phase2 GEMM2 (Pf[a] frags from L2)       -> R(bf16) + F(f32)
//   phase3 GEMM3 (Pb[a] frags from L2)       -> indiv += relu; F -> out (nt)
__global__ __launch_bounds__(512, 2)
void fused_main(const float* __restrict__ img, const float* __restrict__ bias,
                const bf16_t* __restrict__ edgeT,
                const bf16_t* __restrict__ W1f, const bf16_t* __restrict__ W2f,
                const bf16_t* __restrict__ Pff, const bf16_t* __restrict__ Pbf,
                const float* __restrict__ sw, float* __restrict__ out)
{
    __shared__ bf16_t E[2][32 * 256];   // 2 x 16 KB edge dbuf
    __shared__ bf16_t G[32 * 256];      // 16 KB agg
    __shared__ bf16_t R[32 * 256];      // 16 KB attr bf16
    __shared__ float  F[32 * 256];      // 32 KB attr f32 (store bounce)

    const int tid = threadIdx.x;
    const int lane = tid & 63;
    const int wc = tid >> 6;            // 0..7: 32-col slice
    const int lr = lane & 15;
    const int lhi = lane >> 4;
    const int brow0 = blockIdx.x * 32;
    const int sr = tid >> 4;            // staging row 0..31
    const int c16 = (tid & 15) * 16;    // staging col base

    // ---- prologue: img -> E[0] (bf16 swz)
    {
        const float* ip = img + (size_t)(brow0 + sr) * ND + c16;
        f32x4 v0 = *(const f32x4*)(ip + 0), v1 = *(const f32x4*)(ip + 4);
        f32x4 v2 = *(const f32x4*)(ip + 8), v3 = *(const f32x4*)(ip + 12);
        *(bf16x8*)&E[0][swz(sr, c16)] = cvt8(v0, v1);
        *(bf16x8*)&E[0][swz(sr, c16 + 8)] = cvt8(v2, v3);
    }
    __syncthreads();

    // ---- T = img @ W1^T + bias (W1 in regs, then overwritten by W2)
    bf16x8 Wr[2][8];
#pragma unroll
    for (int ni = 0; ni < 2; ++ni)
#pragma unroll
        for (int ks = 0; ks < 8; ++ks)
            Wr[ni][ks] = *(const bf16x8*)&W1f[(((wc * 2 + ni) * 8 + ks) * 64 + lane) * 8];

    f32x4 T[2][2];
#pragma unroll
    for (int ni = 0; ni < 2; ++ni) {
        float bz = bias[wc * 32 + ni * 16 + lr];
        T[0][ni] = (f32x4){bz, bz, bz, bz};
        T[1][ni] = (f32x4){bz, bz, bz, bz};
    }
    gemm32r(&E[0][0], Wr, T, lane);

#pragma unroll
    for (int ni = 0; ni < 2; ++ni)
#pragma unroll
        for (int ks = 0; ks < 8; ++ks)
            Wr[ni][ks] = *(const bf16x8*)&W2f[(((wc * 2 + ni) * 8 + ks) * 64 + lane) * 8];
    __syncthreads();                    // E[0] free

    // ---- edge(a=0) -> E[0]
    {
        const bf16_t* ep = edgeT + ((size_t)0 * NB + brow0 + sr) * ND + c16;
        *(bf16x8*)&E[0][swz(sr, c16)] = *(const bf16x8*)ep;
        *(bf16x8*)&E[0][swz(sr, c16 + 8)] = *(const bf16x8*)(ep + 8);
    }
    __syncthreads();

    f32x4 indiv[2][2];
#pragma unroll
    for (int mi = 0; mi < 2; ++mi)
#pragma unroll
        for (int ni = 0; ni < 2; ++ni)
            indiv[mi][ni] = (f32x4){0.f, 0.f, 0.f, 0.f};

    for (int a = 0; a < NA; ++a) {
        const int cur = a & 1;
        const bool pf = (a + 1 < NA);
        f32x4 acc[2][2];

        // ---- phase 1: issue edge(a+1) loads; GEMM1 = T + edge @ W2^T (regs B)
        bf16x8 elo, ehi;
        if (pf) {
            const bf16_t* ep = edgeT + ((size_t)(a + 1) * NB + brow0 + sr) * ND + c16;
            elo = *(const bf16x8*)ep;
            ehi = *(const bf16x8*)(ep + 8);
        }
#pragma unroll
        for (int mi = 0; mi < 2; ++mi)
#pragma unroll
            for (int ni = 0; ni < 2; ++ni)
                acc[mi][ni] = T[mi][ni];
        gemm32r(&E[cur][0], Wr, acc, lane);
#pragma unroll
        for (int mi = 0; mi < 2; ++mi)
#pragma unroll
            for (int ni = 0; ni < 2; ++ni)
#pragma unroll
                for (int j = 0; j < 4; ++j)
                    G[swz(mi * 16 + lhi * 4 + j, wc * 32 + ni * 16 + lr)] = (bf16_t)acc[mi][ni][j];
        if (pf) {   // commit edge(a+1); HBM latency hidden under GEMM1
            *(bf16x8*)&E[cur ^ 1][swz(sr, c16)] = elo;
            *(bf16x8*)&E[cur ^ 1][swz(sr, c16 + 8)] = ehi;
        }
        __syncthreads();

        // ---- phase 2: attr = agg @ Pf[a] -> R (bf16 swz) + F (f32 swz)
#pragma unroll
        for (int mi = 0; mi < 2; ++mi)
#pragma unroll
            for (int ni = 0; ni < 2; ++ni)
                acc[mi][ni] = (f32x4){0.f, 0.f, 0.f, 0.f};
        gemm32g(&G[0], Pff + (size_t)a * 65536, acc, lane, wc);
#pragma unroll
        for (int mi = 0; mi < 2; ++mi)
#pragma unroll
            for (int ni = 0; ni < 2; ++ni)
#pragma unroll
                for (int j = 0; j < 4; ++j) {
                    int r = mi * 16 + lhi * 4 + j;
                    int c = wc * 32 + ni * 16 + lr;
                    float v = acc[mi][ni][j];
                    R[swz(r, c)] = (bf16_t)v;
                    F[r * 256 + (c ^ ((r & 7) << 2))] = v;
                }
        __syncthreads();

        // ---- phase 3: proj = relu(attr @ Pb[a]); indiv += proj*sw; F -> out
#pragma unroll
        for (int mi = 0; mi < 2; ++mi)
#pragma unroll
            for (int ni = 0; ni < 2; ++ni)
                acc[mi][ni] = (f32x4){0.f, 0.f, 0.f, 0.f};
        gemm32g(&R[0], Pbf + (size_t)a * 65536, acc, lane, wc);
        const float swa = sw[a];
#pragma unroll
        for (int mi = 0; mi < 2; ++mi)
#pragma unroll
            for (int ni = 0; ni < 2; ++ni)
#pragma unroll
                for (int j = 0; j < 4; ++j)
                    indiv[mi][ni][j] += fmaxf(acc[mi][ni][j], 0.f) * swa;
        {
            float* op = out + (size_t)(brow0 + sr) * (NA * ND) + (size_t)a * ND + c16;
#pragma unroll
            for (int q = 0; q < 4; ++q) {
                f32x4 v = *(const f32x4*)&F[sr * 256 + ((c16 + q * 4) ^ ((sr & 7) << 2))];
                __builtin_nontemporal_store(v.x, op + q * 4 + 0);
                __builtin_nontemporal_store(v.y, op + q * 4 + 1);
                __builtin_nontemporal_store(v.z, op + q * 4 + 2);
                __builtin_nontemporal_store(v.w, op + q * 4 + 3);
            }
        }
        __syncthreads();
    }

    // ---- individual_embeddings
#pragma unroll
    for (int mi = 0; mi < 2; ++mi)
#pragma unroll
        for (int ni = 0; ni < 2; ++ni)
#pragma unroll
            for (int j = 0; j < 4; ++j) {
                int r = mi * 16 + lhi * 4 + j;
                int c = wc * 32 + ni * 16 + lr;
                out[(size_t)NB * NA * ND + (size_t)(brow0 + r) * ND + c] = indiv[mi][ni][j];
            }
}

extern "C" void kernel_launch(void* const* d_in, const int* in_sizes, int n_in,
                              void* d_out, int out_size, void* d_ws, size_t ws_size,
                              hipStream_t stream)
{
    const float* img  = (const float*)d_in[0];
    const float* edge = (const float*)d_in[1];
    const float* Wagg = (const float*)d_in[2];
    const float* bagg = (const float*)d_in[3];
    const float* Pf   = (const float*)d_in[4];
    const float* Pb   = (const float*)d_in[5];
    const float* sw   = (const float*)d_in[6];
    float* out = (float*)d_out;

    char* ws = (char*)d_ws;
    bf16_t* W1f = (bf16_t*)(ws);                   // 128 KB fragment layout
    bf16_t* W2f = (bf16_t*)(ws + 131072);          // 128 KB
    bf16_t* Pff = (bf16_t*)(ws + 262144);          // 2 MB
    bf16_t* Pbf = (bf16_t*)(ws + 2359296);         // 2 MB
    bf16_t* edT = (bf16_t*)(ws + 4456448);         // 134.2 MB [a][b][d] bf16
    // temps alias edT (dead before edge_tr runs; stream-ordered)
    bf16_t* Ptf = (bf16_t*)(ws + 4456448);         // 2 MB row-major temp
    bf16_t* Ptb = (bf16_t*)(ws + 6553600);         // 2 MB row-major temp

    prep_wfrag<<<64, 256, 0, stream>>>(Wagg, W1f, W2f);
    transpose_P<<<2048, 256, 0, stream>>>(Pf, Pb, Ptf, Ptb);
    prep_pfrag<<<512, 256, 0, stream>>>(Ptf, Pff);
    prep_pfrag<<<512, 256, 0, stream>>>(Ptb, Pbf);
    edge_tr<<<32768, 256, 0, stream>>>(edge, edT);
    fused_main<<<NB / 32, 512, 0, stream>>>(img, bagg, edT, W1f, W2f, Pff, Pbf, sw, out);
}